// Round 4
// baseline (170.376 us; speedup 1.0000x reference)
//
#include <hip/hip_runtime.h>
#include <hip/hip_bf16.h>

#define NPTS 8192
#define DDIM 128
#define MARGIN 0.2f
#define NEG_FLOOR 0.6f
#define SENT -1e30f
#define NCHUNK 16
#define CHUNK (NPTS / NCHUNK)   // 512

typedef __attribute__((ext_vector_type(8))) short short8;
typedef __attribute__((ext_vector_type(4))) float f32x4;
typedef __attribute__((ext_vector_type(4))) unsigned int uint4v;
typedef __attribute__((ext_vector_type(4))) unsigned short ushort4v;

// ws layout (bytes):
//   xb      : [0, 2 MiB)                       bf16 X
//   mp_part : 2MiB + [0, 512K)                 float [NCHUNK][NPTS]
//   mn_part : +512K                            float [NCHUNK][NPTS]
//   sum_part: +1M                              float [NCHUNK][NPTS]
//   flg_part: +1.5M                            int   [NCHUNK][NPTS]
//   maxpos  : +2M                              float [NPTS]
//   maxneg  : +2M+32K                          float [NPTS]

__device__ __forceinline__ unsigned short f2bf(unsigned u) {
    return (unsigned short)((u + 0x7FFFu + ((u >> 16) & 1u)) >> 16);
}

__global__ __launch_bounds__(256) void k_convert(const uint4v* __restrict__ x,
                                                 ushort4v* __restrict__ xb) {
    int i = blockIdx.x * 256 + threadIdx.x;
    uint4v u = x[i];
    ushort4v o;
    o.x = f2bf(u.x); o.y = f2bf(u.y); o.z = f2bf(u.z); o.w = f2bf(u.w);
    xb[i] = o;
}

// ---- B-tile (32 cols) register buffer + loader -------------------------
struct BTile {
    short8 b[2][4];
    int    tj[2];
};

__device__ __forceinline__ void load_btile(const unsigned short* __restrict__ xb,
                                           const int* __restrict__ tg,
                                           int j0, int lr, int hi, BTile& t) {
#pragma unroll
    for (int jt = 0; jt < 2; ++jt) {
        t.tj[jt] = tg[j0 + jt * 16 + lr];
        const unsigned short* p = xb + (j0 + jt * 16 + lr) * DDIM + hi * 8;
#pragma unroll
        for (int ks = 0; ks < 4; ++ks)
            t.b[jt][ks] = *(const short8*)(p + ks * 32);
    }
}

// 1-wave blocks; wave owns 32 rows x one 512-col chunk, software-pipelined.
__global__ __launch_bounds__(64, 3) void k_pass1(const unsigned short* __restrict__ xb,
                                                 const int* __restrict__ tg,
                                                 float* __restrict__ mp_part,
                                                 float* __restrict__ mn_part) {
    int lane  = threadIdx.x;
    int wv    = blockIdx.x;            // [0, 4096)
    int chunk = wv & (NCHUNK - 1);
    int i0    = (wv >> 4) * 32;
    int lr    = lane & 15;
    int hi    = lane >> 4;

    short8 a[2][4];
#pragma unroll
    for (int rg = 0; rg < 2; ++rg)
#pragma unroll
        for (int ks = 0; ks < 4; ++ks)
            a[rg][ks] = *(const short8*)(xb + (i0 + rg * 16 + lr) * DDIM + ks * 32 + hi * 8);

    int trow[2][4];
#pragma unroll
    for (int rg = 0; rg < 2; ++rg)
#pragma unroll
        for (int r = 0; r < 4; ++r)
            trow[rg][r] = tg[i0 + rg * 16 + hi * 4 + r];

    float mp[2][4], mn[2][4];
#pragma unroll
    for (int rg = 0; rg < 2; ++rg)
#pragma unroll
        for (int r = 0; r < 4; ++r) { mp[rg][r] = SENT; mn[rg][r] = SENT; }

    int jbeg = chunk * CHUNK, jend = jbeg + CHUNK;

    BTile cur, nxt;
    load_btile(xb, tg, jbeg, lr, hi, cur);

#pragma unroll 2
    for (int j0 = jbeg; j0 < jend; j0 += 32) {
        int jn = j0 + 32;
        load_btile(xb, tg, (jn < jend) ? jn : jbeg, lr, hi, nxt);

        f32x4 acc[2][2] = {{{0.f,0.f,0.f,0.f},{0.f,0.f,0.f,0.f}},
                           {{0.f,0.f,0.f,0.f},{0.f,0.f,0.f,0.f}}};
#pragma unroll
        for (int ks = 0; ks < 4; ++ks)
#pragma unroll
            for (int rg = 0; rg < 2; ++rg)
#pragma unroll
                for (int jt = 0; jt < 2; ++jt)
                    acc[rg][jt] = __builtin_amdgcn_mfma_f32_16x16x32_bf16(a[rg][ks], cur.b[jt][ks], acc[rg][jt], 0, 0, 0);

#pragma unroll
        for (int rg = 0; rg < 2; ++rg)
#pragma unroll
            for (int jt = 0; jt < 2; ++jt)
#pragma unroll
                for (int r = 0; r < 4; ++r) {
                    int row   = i0 + rg * 16 + hi * 4 + r;
                    int col   = j0 + jt * 16 + lr;
                    bool same = (cur.tj[jt] == trow[rg][r]);
                    bool diag = (col == row);
                    float s   = acc[rg][jt][r];
                    mp[rg][r] = fmaxf(mp[rg][r], (same && !diag) ? s : SENT);
                    mn[rg][r] = fmaxf(mn[rg][r], same ? SENT : s);
                }

#pragma unroll
        for (int jt = 0; jt < 2; ++jt) {
            cur.tj[jt] = nxt.tj[jt];
#pragma unroll
            for (int ks = 0; ks < 4; ++ks) cur.b[jt][ks] = nxt.b[jt][ks];
        }
    }

#pragma unroll
    for (int off = 1; off < 16; off <<= 1)
#pragma unroll
        for (int rg = 0; rg < 2; ++rg)
#pragma unroll
            for (int r = 0; r < 4; ++r) {
                mp[rg][r] = fmaxf(mp[rg][r], __shfl_xor(mp[rg][r], off, 64));
                mn[rg][r] = fmaxf(mn[rg][r], __shfl_xor(mn[rg][r], off, 64));
            }
    if (lr == 0) {
#pragma unroll
        for (int rg = 0; rg < 2; ++rg)
#pragma unroll
            for (int r = 0; r < 4; ++r) {
                int row = i0 + rg * 16 + hi * 4 + r;
                mp_part[chunk * NPTS + row] = mp[rg][r];
                mn_part[chunk * NPTS + row] = mn[rg][r];
            }
    }
}

__global__ __launch_bounds__(256) void k_red1(const float* __restrict__ mp_part,
                                              const float* __restrict__ mn_part,
                                              float* __restrict__ maxpos,
                                              float* __restrict__ maxneg) {
    int row = blockIdx.x * 256 + threadIdx.x;
    float mp = SENT, mn = SENT;
#pragma unroll
    for (int c = 0; c < NCHUNK; ++c) {
        mp = fmaxf(mp, mp_part[c * NPTS + row]);
        mn = fmaxf(mn, mn_part[c * NPTS + row]);
    }
    maxpos[row] = mp;
    maxneg[row] = mn;
}

__global__ __launch_bounds__(64, 3) void k_pass2(const unsigned short* __restrict__ xb,
                                                 const int* __restrict__ tg,
                                                 const float* __restrict__ maxpos,
                                                 const float* __restrict__ maxneg,
                                                 float* __restrict__ sum_part,
                                                 int* __restrict__ flg_part) {
    int lane  = threadIdx.x;
    int wv    = blockIdx.x;
    int chunk = wv & (NCHUNK - 1);
    int i0    = (wv >> 4) * 32;
    int lr    = lane & 15;
    int hi    = lane >> 4;

    short8 a[2][4];
#pragma unroll
    for (int rg = 0; rg < 2; ++rg)
#pragma unroll
        for (int ks = 0; ks < 4; ++ks)
            a[rg][ks] = *(const short8*)(xb + (i0 + rg * 16 + lr) * DDIM + ks * 32 + hi * 8);

    int trow[2][4];
    float pos_lim[2][4], neg_th[2][4];
#pragma unroll
    for (int rg = 0; rg < 2; ++rg)
#pragma unroll
        for (int r = 0; r < 4; ++r) {
            int row        = i0 + rg * 16 + hi * 4 + r;
            trow[rg][r]    = tg[row];
            pos_lim[rg][r] = maxneg[row] + MARGIN;
            neg_th[rg][r]  = fmaxf(NEG_FLOOR, maxpos[row]) - MARGIN;
        }

    float sum[2][4] = {{0.f,0.f,0.f,0.f},{0.f,0.f,0.f,0.f}};
    int   an = 0;   // bitmask: bit (rg*4+r)

    int jbeg = chunk * CHUNK, jend = jbeg + CHUNK;

    BTile cur, nxt;
    load_btile(xb, tg, jbeg, lr, hi, cur);

#pragma unroll 2
    for (int j0 = jbeg; j0 < jend; j0 += 32) {
        int jn = j0 + 32;
        load_btile(xb, tg, (jn < jend) ? jn : jbeg, lr, hi, nxt);

        f32x4 acc[2][2] = {{{0.f,0.f,0.f,0.f},{0.f,0.f,0.f,0.f}},
                           {{0.f,0.f,0.f,0.f},{0.f,0.f,0.f,0.f}}};
#pragma unroll
        for (int ks = 0; ks < 4; ++ks)
#pragma unroll
            for (int rg = 0; rg < 2; ++rg)
#pragma unroll
                for (int jt = 0; jt < 2; ++jt)
                    acc[rg][jt] = __builtin_amdgcn_mfma_f32_16x16x32_bf16(a[rg][ks], cur.b[jt][ks], acc[rg][jt], 0, 0, 0);

#pragma unroll
        for (int rg = 0; rg < 2; ++rg)
#pragma unroll
            for (int jt = 0; jt < 2; ++jt)
#pragma unroll
                for (int r = 0; r < 4; ++r) {
                    int row   = i0 + rg * 16 + hi * 4 + r;
                    int col   = j0 + jt * 16 + lr;
                    bool same = (cur.tj[jt] == trow[rg][r]);
                    bool diag = (col == row);
                    float s   = acc[rg][jt][r];
                    bool psel = same && !diag && (s < pos_lim[rg][r]);
                    bool nsel = !same && (s > neg_th[rg][r]);
                    float contrib = psel ? (1.0f - s) : (nsel ? s : 0.0f);
                    sum[rg][r] += contrib;
                    an |= nsel ? (1 << (rg * 4 + r)) : 0;
                }

#pragma unroll
        for (int jt = 0; jt < 2; ++jt) {
            cur.tj[jt] = nxt.tj[jt];
#pragma unroll
            for (int ks = 0; ks < 4; ++ks) cur.b[jt][ks] = nxt.b[jt][ks];
        }
    }

#pragma unroll
    for (int off = 1; off < 16; off <<= 1) {
        an |= __shfl_xor(an, off, 64);
#pragma unroll
        for (int rg = 0; rg < 2; ++rg)
#pragma unroll
            for (int r = 0; r < 4; ++r)
                sum[rg][r] += __shfl_xor(sum[rg][r], off, 64);
    }
    if (lr == 0) {
#pragma unroll
        for (int rg = 0; rg < 2; ++rg)
#pragma unroll
            for (int r = 0; r < 4; ++r) {
                int row = i0 + rg * 16 + hi * 4 + r;
                sum_part[chunk * NPTS + row] = sum[rg][r];
                flg_part[chunk * NPTS + row] = (an >> (rg * 4 + r)) & 1;
            }
    }
}

__global__ __launch_bounds__(256) void k_final(const float* __restrict__ maxpos,
                                               const float* __restrict__ sum_part,
                                               const int* __restrict__ flg_part,
                                               float* __restrict__ out) {
    __shared__ float sf[256];
    __shared__ int   si[256];
    int t = threadIdx.x;
    float s = 0.f;
    int   c = 0;
    for (int row = t; row < NPTS; row += 256) {
        bool hp = maxpos[row] > -1e29f;
        float rs = 0.f;
        int   fl = 0;
#pragma unroll
        for (int ch = 0; ch < NCHUNK; ++ch) {
            rs += sum_part[ch * NPTS + row];
            fl |= flg_part[ch * NPTS + row];
        }
        s += hp ? rs : 0.f;
        c += (hp && fl) ? 1 : 0;
    }
    sf[t] = s;
    si[t] = c;
    __syncthreads();
    for (int off = 128; off > 0; off >>= 1) {
        if (t < off) { sf[t] += sf[t + off]; si[t] += si[t + off]; }
        __syncthreads();
    }
    if (t == 0) {
        out[0] = sf[0] / (float)NPTS;
        out[1] = (float)si[0];
    }
}

extern "C" void kernel_launch(void* const* d_in, const int* in_sizes, int n_in,
                              void* d_out, int out_size, void* d_ws, size_t ws_size,
                              hipStream_t stream) {
    const float* x  = (const float*)d_in[0];
    const int*   tg = (const int*)d_in[1];
    float* out = (float*)d_out;

    unsigned short* xb = (unsigned short*)d_ws;
    char* base = (char*)d_ws + (size_t)NPTS * DDIM * 2;
    float* mp_part  = (float*)(base);
    float* mn_part  = (float*)(base + 1 * (NCHUNK * NPTS * 4));
    float* sum_part = (float*)(base + 2 * (NCHUNK * NPTS * 4));
    int*   flg_part = (int*)  (base + 3 * (NCHUNK * NPTS * 4));
    float* maxpos   = (float*)(base + 4 * (NCHUNK * NPTS * 4));
    float* maxneg   = (float*)(base + 4 * (NCHUNK * NPTS * 4) + NPTS * 4);

    k_convert<<<(NPTS * DDIM / 4) / 256, 256, 0, stream>>>((const uint4v*)x, (ushort4v*)xb);
    k_pass1<<<(NPTS / 32) * NCHUNK, 64, 0, stream>>>(xb, tg, mp_part, mn_part);
    k_red1<<<NPTS / 256, 256, 0, stream>>>(mp_part, mn_part, maxpos, maxneg);
    k_pass2<<<(NPTS / 32) * NCHUNK, 64, 0, stream>>>(xb, tg, maxpos, maxneg, sum_part, flg_part);
    k_final<<<1, 256, 0, stream>>>(maxpos, sum_part, flg_part, out);
}

// Round 5
// 97.286 us; speedup vs baseline: 1.7513x; 1.7513x over previous
//
#include <hip/hip_runtime.h>
#include <hip/hip_bf16.h>

#define NPTS 8192
#define DDIM 128
#define MARGIN 0.2f
#define NEG_FLOOR 0.6f
#define SENT -1e30f
#define NCHUNK 16
#define CHUNK (NPTS / NCHUNK)      // 512 cols per chunk
#define BM 128                     // rows per block (4 waves x 32)
#define JT 64                      // cols staged per step
#define NSTEP (CHUNK / JT)         // 8

typedef __attribute__((ext_vector_type(8))) short short8;
typedef __attribute__((ext_vector_type(4))) float f32x4;
typedef __attribute__((ext_vector_type(4))) unsigned int uint4v;
typedef __attribute__((ext_vector_type(4))) unsigned short ushort4v;

// ws layout (bytes):
//   xb      : [0, 2 MiB)            bf16 X
//   mp_part : +0   float [16][NPTS]
//   mn_part : +512K
//   sum_part: +1M
//   flg_part: +1.5M
//   maxpos  : +2M   float [NPTS]
//   maxneg  : +2M+32K

__device__ __forceinline__ unsigned short f2bf(unsigned u) {
    return (unsigned short)((u + 0x7FFFu + ((u >> 16) & 1u)) >> 16);
}

__global__ __launch_bounds__(256) void k_convert(const uint4v* __restrict__ x,
                                                 ushort4v* __restrict__ xb) {
    int i = blockIdx.x * 256 + threadIdx.x;
    uint4v u = x[i];
    ushort4v o;
    o.x = f2bf(u.x); o.y = f2bf(u.y); o.z = f2bf(u.z); o.w = f2bf(u.w);
    xb[i] = o;
}

// async global->LDS, 16B per lane; LDS dest = wave-uniform base + lane*16
__device__ __forceinline__ void gload16(const unsigned char* g, unsigned char* l) {
    __builtin_amdgcn_global_load_lds(
        (const __attribute__((address_space(1))) unsigned int*)(const void*)g,
        (__attribute__((address_space(3))) unsigned int*)(void*)l, 16, 0, 0);
}

// LDS B-tile layout = fragment order: slot(cg, ks, lane) at byte
// cg*4096 + ks*1024 + lane*16, holding global bytes
// (j0 + cg*16 + (lane&15))*256 + ks*64 + (lane>>4)*16.
// Staged by wave w (=cg), issue r (=ks): per-lane source is the permuted
// global address; every hot ds_read_b128 is then base + lane*16 (conflict-free).

__global__ __launch_bounds__(256, 4) void k_pass1(const unsigned short* __restrict__ xb,
                                                  const int* __restrict__ tg,
                                                  float* __restrict__ mp_part,
                                                  float* __restrict__ mn_part) {
    __shared__ __align__(16) unsigned char smB[JT * 256];  // 16 KB
    __shared__ int ts[CHUNK];                              // 2 KB

    const unsigned char* xc = (const unsigned char*)xb;
    int tid  = threadIdx.x;
    int lane = tid & 63, w = tid >> 6, lr = lane & 15, hi = lane >> 4;
    int bb    = blockIdx.x;
    int chunk = bb & (NCHUNK - 1);
    int rb    = bb >> 4;
    int i0    = rb * BM;
    int jbase = chunk * CHUNK;

    ts[tid]       = tg[jbase + tid];
    ts[tid + 256] = tg[jbase + 256 + tid];

    int rowbase = i0 + w * 32;
    short8 a[2][4];
#pragma unroll
    for (int rg = 0; rg < 2; ++rg)
#pragma unroll
        for (int ks = 0; ks < 4; ++ks)
            a[rg][ks] = *(const short8*)(xc + (size_t)(rowbase + rg * 16 + lr) * 256 + ks * 64 + hi * 16);

    int trow[2][4];
#pragma unroll
    for (int rg = 0; rg < 2; ++rg)
#pragma unroll
        for (int r = 0; r < 4; ++r)
            trow[rg][r] = tg[rowbase + rg * 16 + hi * 4 + r];

    float mp[2][4], mn[2][4];
#pragma unroll
    for (int rg = 0; rg < 2; ++rg)
#pragma unroll
        for (int r = 0; r < 4; ++r) { mp[rg][r] = SENT; mn[rg][r] = SENT; }

    for (int step = 0; step < NSTEP; ++step) {
        int j0 = jbase + step * JT;
        __syncthreads();  // prior compute done (iter 0: ts ready)
        const unsigned char* src = xc + (size_t)(j0 + w * 16 + lr) * 256 + hi * 16;
#pragma unroll
        for (int r = 0; r < 4; ++r)
            gload16(src + r * 64, smB + w * 4096 + r * 1024);
        __syncthreads();  // vmcnt(0) drained before barrier -> tile ready

#pragma unroll
        for (int cg = 0; cg < 4; ++cg) {
            int col = j0 + cg * 16 + lr;
            int tjv = ts[step * 64 + cg * 16 + lr];
            short8 b0 = *(const short8*)(smB + cg * 4096 + 0 * 1024 + lane * 16);
            short8 b1 = *(const short8*)(smB + cg * 4096 + 1 * 1024 + lane * 16);
            short8 b2 = *(const short8*)(smB + cg * 4096 + 2 * 1024 + lane * 16);
            short8 b3 = *(const short8*)(smB + cg * 4096 + 3 * 1024 + lane * 16);
            f32x4 acc0 = {0.f, 0.f, 0.f, 0.f}, acc1 = {0.f, 0.f, 0.f, 0.f};
            acc0 = __builtin_amdgcn_mfma_f32_16x16x32_bf16(a[0][0], b0, acc0, 0, 0, 0);
            acc1 = __builtin_amdgcn_mfma_f32_16x16x32_bf16(a[1][0], b0, acc1, 0, 0, 0);
            acc0 = __builtin_amdgcn_mfma_f32_16x16x32_bf16(a[0][1], b1, acc0, 0, 0, 0);
            acc1 = __builtin_amdgcn_mfma_f32_16x16x32_bf16(a[1][1], b1, acc1, 0, 0, 0);
            acc0 = __builtin_amdgcn_mfma_f32_16x16x32_bf16(a[0][2], b2, acc0, 0, 0, 0);
            acc1 = __builtin_amdgcn_mfma_f32_16x16x32_bf16(a[1][2], b2, acc1, 0, 0, 0);
            acc0 = __builtin_amdgcn_mfma_f32_16x16x32_bf16(a[0][3], b3, acc0, 0, 0, 0);
            acc1 = __builtin_amdgcn_mfma_f32_16x16x32_bf16(a[1][3], b3, acc1, 0, 0, 0);
#pragma unroll
            for (int rg = 0; rg < 2; ++rg) {
                f32x4 acc = rg ? acc1 : acc0;
                int dv = col - (rowbase + rg * 16 + hi * 4);  // diag when dv == r
#pragma unroll
                for (int r = 0; r < 4; ++r) {
                    bool same = (tjv == trow[rg][r]);
                    float s   = acc[r];
                    mp[rg][r] = fmaxf(mp[rg][r], (same && dv != r) ? s : SENT);
                    mn[rg][r] = fmaxf(mn[rg][r], same ? SENT : s);
                }
            }
        }
    }

#pragma unroll
    for (int off = 1; off < 16; off <<= 1)
#pragma unroll
        for (int rg = 0; rg < 2; ++rg)
#pragma unroll
            for (int r = 0; r < 4; ++r) {
                mp[rg][r] = fmaxf(mp[rg][r], __shfl_xor(mp[rg][r], off, 64));
                mn[rg][r] = fmaxf(mn[rg][r], __shfl_xor(mn[rg][r], off, 64));
            }
    if (lr == 0) {
#pragma unroll
        for (int rg = 0; rg < 2; ++rg)
#pragma unroll
            for (int r = 0; r < 4; ++r) {
                int row = rowbase + rg * 16 + hi * 4 + r;
                mp_part[chunk * NPTS + row] = mp[rg][r];
                mn_part[chunk * NPTS + row] = mn[rg][r];
            }
    }
}

__global__ __launch_bounds__(256) void k_red1(const float* __restrict__ mp_part,
                                              const float* __restrict__ mn_part,
                                              float* __restrict__ maxpos,
                                              float* __restrict__ maxneg) {
    int row = blockIdx.x * 256 + threadIdx.x;
    float mp = SENT, mn = SENT;
#pragma unroll
    for (int c = 0; c < NCHUNK; ++c) {
        mp = fmaxf(mp, mp_part[c * NPTS + row]);
        mn = fmaxf(mn, mn_part[c * NPTS + row]);
    }
    maxpos[row] = mp;
    maxneg[row] = mn;
}

__global__ __launch_bounds__(256, 4) void k_pass2(const unsigned short* __restrict__ xb,
                                                  const int* __restrict__ tg,
                                                  const float* __restrict__ maxpos,
                                                  const float* __restrict__ maxneg,
                                                  float* __restrict__ sum_part,
                                                  int* __restrict__ flg_part) {
    __shared__ __align__(16) unsigned char smB[JT * 256];
    __shared__ int ts[CHUNK];

    const unsigned char* xc = (const unsigned char*)xb;
    int tid  = threadIdx.x;
    int lane = tid & 63, w = tid >> 6, lr = lane & 15, hi = lane >> 4;
    int bb    = blockIdx.x;
    int chunk = bb & (NCHUNK - 1);
    int rb    = bb >> 4;
    int i0    = rb * BM;
    int jbase = chunk * CHUNK;

    ts[tid]       = tg[jbase + tid];
    ts[tid + 256] = tg[jbase + 256 + tid];

    int rowbase = i0 + w * 32;
    short8 a[2][4];
#pragma unroll
    for (int rg = 0; rg < 2; ++rg)
#pragma unroll
        for (int ks = 0; ks < 4; ++ks)
            a[rg][ks] = *(const short8*)(xc + (size_t)(rowbase + rg * 16 + lr) * 256 + ks * 64 + hi * 16);

    int trow[2][4];
    float pos_lim[2][4], neg_th[2][4];
#pragma unroll
    for (int rg = 0; rg < 2; ++rg)
#pragma unroll
        for (int r = 0; r < 4; ++r) {
            int row         = rowbase + rg * 16 + hi * 4 + r;
            trow[rg][r]     = tg[row];
            pos_lim[rg][r]  = maxneg[row] + MARGIN;
            neg_th[rg][r]   = fmaxf(NEG_FLOOR, maxpos[row]) - MARGIN;
        }

    float sum[2][4] = {{0.f,0.f,0.f,0.f},{0.f,0.f,0.f,0.f}};
    int   an = 0;

    for (int step = 0; step < NSTEP; ++step) {
        int j0 = jbase + step * JT;
        __syncthreads();
        const unsigned char* src = xc + (size_t)(j0 + w * 16 + lr) * 256 + hi * 16;
#pragma unroll
        for (int r = 0; r < 4; ++r)
            gload16(src + r * 64, smB + w * 4096 + r * 1024);
        __syncthreads();

#pragma unroll
        for (int cg = 0; cg < 4; ++cg) {
            int col = j0 + cg * 16 + lr;
            int tjv = ts[step * 64 + cg * 16 + lr];
            short8 b0 = *(const short8*)(smB + cg * 4096 + 0 * 1024 + lane * 16);
            short8 b1 = *(const short8*)(smB + cg * 4096 + 1 * 1024 + lane * 16);
            short8 b2 = *(const short8*)(smB + cg * 4096 + 2 * 1024 + lane * 16);
            short8 b3 = *(const short8*)(smB + cg * 4096 + 3 * 1024 + lane * 16);
            f32x4 acc0 = {0.f, 0.f, 0.f, 0.f}, acc1 = {0.f, 0.f, 0.f, 0.f};
            acc0 = __builtin_amdgcn_mfma_f32_16x16x32_bf16(a[0][0], b0, acc0, 0, 0, 0);
            acc1 = __builtin_amdgcn_mfma_f32_16x16x32_bf16(a[1][0], b0, acc1, 0, 0, 0);
            acc0 = __builtin_amdgcn_mfma_f32_16x16x32_bf16(a[0][1], b1, acc0, 0, 0, 0);
            acc1 = __builtin_amdgcn_mfma_f32_16x16x32_bf16(a[1][1], b1, acc1, 0, 0, 0);
            acc0 = __builtin_amdgcn_mfma_f32_16x16x32_bf16(a[0][2], b2, acc0, 0, 0, 0);
            acc1 = __builtin_amdgcn_mfma_f32_16x16x32_bf16(a[1][2], b2, acc1, 0, 0, 0);
            acc0 = __builtin_amdgcn_mfma_f32_16x16x32_bf16(a[0][3], b3, acc0, 0, 0, 0);
            acc1 = __builtin_amdgcn_mfma_f32_16x16x32_bf16(a[1][3], b3, acc1, 0, 0, 0);
#pragma unroll
            for (int rg = 0; rg < 2; ++rg) {
                f32x4 acc = rg ? acc1 : acc0;
                int dv = col - (rowbase + rg * 16 + hi * 4);
#pragma unroll
                for (int r = 0; r < 4; ++r) {
                    bool same = (tjv == trow[rg][r]);
                    float s   = acc[r];
                    bool psel = same && (dv != r) && (s < pos_lim[rg][r]);
                    bool nsel = (!same) && (s > neg_th[rg][r]);
                    sum[rg][r] += psel ? (1.0f - s) : (nsel ? s : 0.0f);
                    an |= nsel ? (1 << (rg * 4 + r)) : 0;
                }
            }
        }
    }

#pragma unroll
    for (int off = 1; off < 16; off <<= 1) {
        an |= __shfl_xor(an, off, 64);
#pragma unroll
        for (int rg = 0; rg < 2; ++rg)
#pragma unroll
            for (int r = 0; r < 4; ++r)
                sum[rg][r] += __shfl_xor(sum[rg][r], off, 64);
    }
    if (lr == 0) {
#pragma unroll
        for (int rg = 0; rg < 2; ++rg)
#pragma unroll
            for (int r = 0; r < 4; ++r) {
                int row = rowbase + rg * 16 + hi * 4 + r;
                sum_part[chunk * NPTS + row] = sum[rg][r];
                flg_part[chunk * NPTS + row] = (an >> (rg * 4 + r)) & 1;
            }
    }
}

__global__ __launch_bounds__(256) void k_final(const float* __restrict__ maxpos,
                                               const float* __restrict__ sum_part,
                                               const int* __restrict__ flg_part,
                                               float* __restrict__ out) {
    __shared__ float sf[256];
    __shared__ int   si[256];
    int t = threadIdx.x;
    float s = 0.f;
    int   c = 0;
    for (int row = t; row < NPTS; row += 256) {
        bool hp = maxpos[row] > -1e29f;
        float rs = 0.f;
        int   fl = 0;
#pragma unroll
        for (int ch = 0; ch < NCHUNK; ++ch) {
            rs += sum_part[ch * NPTS + row];
            fl |= flg_part[ch * NPTS + row];
        }
        s += hp ? rs : 0.f;
        c += (hp && fl) ? 1 : 0;
    }
    sf[t] = s;
    si[t] = c;
    __syncthreads();
    for (int off = 128; off > 0; off >>= 1) {
        if (t < off) { sf[t] += sf[t + off]; si[t] += si[t + off]; }
        __syncthreads();
    }
    if (t == 0) {
        out[0] = sf[0] / (float)NPTS;
        out[1] = (float)si[0];
    }
}

extern "C" void kernel_launch(void* const* d_in, const int* in_sizes, int n_in,
                              void* d_out, int out_size, void* d_ws, size_t ws_size,
                              hipStream_t stream) {
    const float* x  = (const float*)d_in[0];
    const int*   tg = (const int*)d_in[1];
    float* out = (float*)d_out;

    unsigned short* xb = (unsigned short*)d_ws;
    char* base = (char*)d_ws + (size_t)NPTS * DDIM * 2;
    float* mp_part  = (float*)(base);
    float* mn_part  = (float*)(base + 1 * (NCHUNK * NPTS * 4));
    float* sum_part = (float*)(base + 2 * (NCHUNK * NPTS * 4));
    int*   flg_part = (int*)  (base + 3 * (NCHUNK * NPTS * 4));
    float* maxpos   = (float*)(base + 4 * (NCHUNK * NPTS * 4));
    float* maxneg   = (float*)(base + 4 * (NCHUNK * NPTS * 4) + NPTS * 4);

    k_convert<<<(NPTS * DDIM / 4) / 256, 256, 0, stream>>>((const uint4v*)x, (ushort4v*)xb);
    k_pass1<<<(NPTS / BM) * NCHUNK, 256, 0, stream>>>(xb, tg, mp_part, mn_part);
    k_red1<<<NPTS / 256, 256, 0, stream>>>(mp_part, mn_part, maxpos, maxneg);
    k_pass2<<<(NPTS / BM) * NCHUNK, 256, 0, stream>>>(xb, tg, maxpos, maxneg, sum_part, flg_part);
    k_final<<<1, 256, 0, stream>>>(maxpos, sum_part, flg_part, out);
}